// Round 2
// baseline (590.719 us; speedup 1.0000x reference)
//
#include <hip/hip_runtime.h>

typedef unsigned short ushort_t;
typedef __attribute__((ext_vector_type(4))) float f32x4;
typedef __attribute__((ext_vector_type(8))) short s16x8;
typedef __attribute__((ext_vector_type(8))) unsigned short u16x8;

#define NB 16         // dialogues
#define NL 54         // utterances per dialogue
#define NT (NB*NL)    // 864
#define NNODE (3*NT)  // 2592
#define NEDGE 912     // hyperedges = 16*(54+3)
#define MATSZ (512*512)
#define INV53 (1.0f/(53.0f + 1e-8f))
#define NBLK 256      // persistent blocks (<= 256 CUs, residency guaranteed)

__device__ __forceinline__ ushort_t f2b(float f){
  union {unsigned int i; float f;} x; x.f = f;
  unsigned int r = (x.i + 0x7fffu + ((x.i>>16)&1u))>>16;
  return (ushort_t)r;
}

__device__ __forceinline__ void async_copy16(const ushort_t* g, ushort_t* l){
  __builtin_amdgcn_global_load_lds((const __attribute__((address_space(1))) void*)g,
                                   (__attribute__((address_space(3))) void*)l, 16, 0, 0);
}

struct MegaArgs {
  const float *A_in,*V_in,*L_in,*qmask,*spk,*fc1_b,*he_w,*ew_w,*attr1,*attr2,*hc_b,*m3_b;
  const float *fc1_W,*hc_W,*m3_W0,*m3_W1,*m3_Ws;
  const int *het;
  ushort_t *WT;
  float *X1,*OUT,*HS,*G,*EB,*Gsum,*Sp,*acc,*dout;
  unsigned int *bar;
};

// Grid-wide barrier: all 256 blocks are co-resident (53KB LDS -> >=3 blk/CU
// capacity = 768 >= 256, so a plain launch cannot partially schedule).
// release fetch_add writes back the XCD L2; acquire load invalidates it
// (gfx940+ agent-scope memory model) -> cross-XCD visibility of plain stores.
__device__ __forceinline__ void gsync(unsigned int* bar, unsigned int tgt){
  __syncthreads();
  if (threadIdx.x==0){
    __hip_atomic_fetch_add(bar, 1u, __ATOMIC_RELEASE, __HIP_MEMORY_SCOPE_AGENT);
    while (__hip_atomic_load(bar, __ATOMIC_RELAXED, __HIP_MEMORY_SCOPE_AGENT) < tgt)
      __builtin_amdgcn_s_sleep(2);
    (void)__hip_atomic_load(bar, __ATOMIC_ACQUIRE, __HIP_MEMORY_SCOPE_AGENT);
  }
  __syncthreads();
}

// ---------------------------------------------------------------------------
// Stage job: transpose+convert one 64x64 tile of one weight matrix.
// job = w*64 + tile; slots 12..15 store combined (Wself - inv*W1).
// ---------------------------------------------------------------------------
__device__ void transpose_job(const MegaArgs& a, int job, char* smem){
  float (*tile)[65] = (float(*)[65])smem;
  int w = job>>6, t = job&63, bx = t>>3, by = t&7;
  const float* src = (w==0) ? a.fc1_W
                   : (w<4)  ? a.hc_W + (size_t)(w-1)*MATSZ
                   : (w<8)  ? a.m3_W0 + (size_t)(w-4)*MATSZ
                   : (w<12) ? a.m3_W1 + (size_t)(w-8)*MATSZ
                            : a.m3_Ws + (size_t)(w-12)*MATSZ;
  const float* src2 = (w>=12) ? a.m3_W1 + (size_t)(w-12)*MATSZ : nullptr;
  ushort_t* dst = a.WT + (size_t)w*MATSZ;
  int r0 = bx*64, c0 = by*64;
  __syncthreads();   // guard LDS reuse across sequential jobs
  #pragma unroll
  for (int j=0;j<16;j++){
    int idx = j*256 + threadIdx.x;
    int r = idx>>6, c = idx&63;
    size_t off = (size_t)(r0+r)*512 + c0 + c;
    float v = src[off];
    if (w>=12) v -= INV53 * src2[off];
    tile[r][c] = v;
  }
  __syncthreads();
  #pragma unroll
  for (int j=0;j<16;j++){
    int idx = j*256 + threadIdx.x;
    int r = idx>>6, c = idx&63;
    dst[(size_t)(c0+r)*512 + r0 + c] = f2b(tile[c][r]);
  }
}

// ---------------------------------------------------------------------------
// GEMM tile 64x128, 4 waves (2x2), per-wave 32x64.  2-phase pipelined,
// double-buffered LDS; B staged via global_load_lds into XOR-swizzled LDS.
// AMODE 0: A = feats (a/v/l + spk_emb), W=fc1
// AMODE 1: A = 2-incidence hyperedge combine from Ebuf
// AMODE 2: zsel 0 -> HS = gin@(Wself - inv*W1)+b;  zsel 1 -> Sp = Gsum@[W0|W1]
// ---------------------------------------------------------------------------
template<int AMODE, bool RELU>
__device__ void gemm_tile(int bx, int by, int zsel,
    const float* Afp, const float* Ebuf,
    const float* inA, const float* inV, const float* inL,
    const float* qmask, const float* spk_emb, const float* he_w,
    const ushort_t* WT, const float* bias,
    float* C0, float* C2, int layer, char* smem)
{
  const int tid = threadIdx.x;
  const int wave = tid>>6, lane = tid&63;
  const int ml = lane&15, quad = lane>>4;
  const int wr = wave>>1, wc = wave&1;
  int row0 = bx*64, col0 = by*128;
  int M = NNODE, cst = 512, cbase = 0;
  const ushort_t* Wsel = WT; float* Cout = C0; const float* bsel = bias;
  const float* Asrc = Afp;
  if (AMODE==2){
    if (zsel==0){ Wsel = WT + (size_t)(12+layer)*MATSZ; Cout = C0; bsel = bias + layer*512; }
    else {
      int colh = bx & 1;
      row0 = (bx>>1)*64;
      Wsel = WT + (size_t)(4 + colh*4 + layer)*MATSZ;
      Cout = C2; bsel = nullptr; M = 96; cst = 1024; cbase = colh*512;
      Asrc = Ebuf;   // Gsum passed in the Ebuf slot
    }
  }

  ushort_t (*As)[64][80]  = (ushort_t(*)[64][80])smem;          // 2*64*80*2 = 20480B
  ushort_t (*Bs)[128*64]  = (ushort_t(*)[128*64])(smem + 20480); // 2*8192*2*2 = 32768B

  const int ar = tid>>3, ac8 = (tid&7)*8;
  const float *sr0=nullptr,*sr1=nullptr,*sp0=nullptr,*sp1=nullptr;
  const float *e10=nullptr,*e20=nullptr,*e11=nullptr,*e21=nullptr;
  float c10=0.f,c20=0.f,c11=0.f,c21=0.f;
  const float *g0=nullptr,*g1=nullptr;
  {
    int n0 = row0+ar;     if (n0 > M-1) n0 = M-1;
    int n1 = row0+ar+32;  if (n1 > M-1) n1 = M-1;
    if (AMODE==0){
      int d=n0/162, rm=n0-d*162, m=rm/54, i=rm-m*54, t=d*54+i;
      sr0 = ((m==0)? inL : (m==1)? inA : inV) + (size_t)t*512;
      if (m==0) sp0 = spk_emb + ((qmask[(i*16+d)*2+1]>qmask[(i*16+d)*2])?512:0);
      d=n1/162; rm=n1-d*162; m=rm/54; i=rm-m*54; t=d*54+i;
      sr1 = ((m==0)? inL : (m==1)? inA : inV) + (size_t)t*512;
      if (m==0) sp1 = spk_emb + ((qmask[(i*16+d)*2+1]>qmask[(i*16+d)*2])?512:0);
    } else if (AMODE==1){
      int d=n0/162, rm=n0-d*162, m=rm/54, i=rm-m*54;
      int em=d*57+m, eu=d*57+3+i;
      float w1=he_w[em], w2=he_w[eu], inv=1.0f/(w1+w2+1e-8f);
      c10=w1*inv; c20=w2*inv; e10=Ebuf+(size_t)em*512; e20=Ebuf+(size_t)eu*512;
      d=n1/162; rm=n1-d*162; m=rm/54; i=rm-m*54;
      em=d*57+m; eu=d*57+3+i;
      w1=he_w[em]; w2=he_w[eu]; inv=1.0f/(w1+w2+1e-8f);
      c11=w1*inv; c21=w2*inv; e11=Ebuf+(size_t)em*512; e21=Ebuf+(size_t)eu*512;
    } else {
      g0 = Asrc + (size_t)n0*512;
      g1 = Asrc + (size_t)n1*512;
    }
  }

  f32x4 acc[2][4];
  #pragma unroll
  for (int mi=0;mi<2;mi++)
    #pragma unroll
    for (int j=0;j<4;j++) acc[mi][j] = (f32x4){0.f,0.f,0.f,0.f};

  const int lr = lane>>3;
  const int lchunk = lane&7;
  const int bswz = (lchunk ^ lr)*8;

  f32x4 p0a,p0b,p1a,p1b;
  f32x4 q0a,q0b,q1a,q1b;

  auto loadA = [&](int kk){
    if (AMODE==0){
      p0a=*(const f32x4*)(sr0+kk+ac8); p0b=*(const f32x4*)(sr0+kk+ac8+4);
      if (sp0){ q0a=*(const f32x4*)(sp0+kk+ac8); q0b=*(const f32x4*)(sp0+kk+ac8+4); }
      p1a=*(const f32x4*)(sr1+kk+ac8); p1b=*(const f32x4*)(sr1+kk+ac8+4);
      if (sp1){ q1a=*(const f32x4*)(sp1+kk+ac8); q1b=*(const f32x4*)(sp1+kk+ac8+4); }
    } else if (AMODE==1){
      p0a=*(const f32x4*)(e10+kk+ac8); p0b=*(const f32x4*)(e10+kk+ac8+4);
      q0a=*(const f32x4*)(e20+kk+ac8); q0b=*(const f32x4*)(e20+kk+ac8+4);
      p1a=*(const f32x4*)(e11+kk+ac8); p1b=*(const f32x4*)(e11+kk+ac8+4);
      q1a=*(const f32x4*)(e21+kk+ac8); q1b=*(const f32x4*)(e21+kk+ac8+4);
    } else {
      p0a=*(const f32x4*)(g0+kk+ac8); p0b=*(const f32x4*)(g0+kk+ac8+4);
      p1a=*(const f32x4*)(g1+kk+ac8); p1b=*(const f32x4*)(g1+kk+ac8+4);
    }
  };

  auto cvtWriteA = [&](int buf){
    u16x8 av0, av1;
    if (AMODE==0){
      f32x4 xa=p0a, xb=p0b;
      if (sp0){
        #pragma unroll
        for(int j=0;j<4;j++){ xa[j]+=q0a[j]; xb[j]+=q0b[j]; }
      }
      #pragma unroll
      for(int j=0;j<4;j++){ av0[j]=f2b(xa[j]); av0[4+j]=f2b(xb[j]); }
      xa=p1a; xb=p1b;
      if (sp1){
        #pragma unroll
        for(int j=0;j<4;j++){ xa[j]+=q1a[j]; xb[j]+=q1b[j]; }
      }
      #pragma unroll
      for(int j=0;j<4;j++){ av1[j]=f2b(xa[j]); av1[4+j]=f2b(xb[j]); }
    } else if (AMODE==1){
      #pragma unroll
      for(int j=0;j<4;j++){ av0[j]=f2b(c10*p0a[j]+c20*q0a[j]); av0[4+j]=f2b(c10*p0b[j]+c20*q0b[j]); }
      #pragma unroll
      for(int j=0;j<4;j++){ av1[j]=f2b(c11*p1a[j]+c21*q1a[j]); av1[4+j]=f2b(c11*p1b[j]+c21*q1b[j]); }
    } else {
      #pragma unroll
      for(int j=0;j<4;j++){ av0[j]=f2b(p0a[j]); av0[4+j]=f2b(p0b[j]); }
      #pragma unroll
      for(int j=0;j<4;j++){ av1[j]=f2b(p1a[j]); av1[4+j]=f2b(p1b[j]); }
    }
    *(u16x8*)&As[buf][ar][ac8]    = av0;
    *(u16x8*)&As[buf][ar+32][ac8] = av1;
  };

  auto stageB = [&](int buf, int kk){
    #pragma unroll
    for (int rep=0; rep<4; rep++){
      int bn0 = wave*32 + rep*8;
      const ushort_t* src = Wsel + (size_t)(col0 + bn0 + lr)*512 + kk + bswz;
      async_copy16(src, &Bs[buf][bn0*64]);
    }
  };

  loadA(0);
  stageB(0, 0);
  cvtWriteA(0);

  int cur = 0;
  #pragma unroll
  for (int t=0; t<8; t++){
    __syncthreads();
    if (t<7){ loadA((t+1)*64); stageB(cur^1, (t+1)*64); }

    #pragma unroll
    for (int kh=0; kh<2; kh++){
      s16x8 a0 = *(const s16x8*)&As[cur][wr*32 + ml][kh*32 + quad*8];
      s16x8 a1 = *(const s16x8*)&As[cur][wr*32 + 16 + ml][kh*32 + quad*8];
      s16x8 b[4];
      #pragma unroll
      for (int j=0;j<4;j++){
        int bn = wc*64 + j*16 + ml;
        b[j] = *(const s16x8*)&Bs[cur][bn*64 + (((kh*4+quad) ^ (bn&7))<<3)];
      }
      #pragma unroll
      for (int j=0;j<4;j++){
        acc[0][j] = __builtin_amdgcn_mfma_f32_16x16x32_bf16(a0,b[j],acc[0][j],0,0,0);
        acc[1][j] = __builtin_amdgcn_mfma_f32_16x16x32_bf16(a1,b[j],acc[1][j],0,0,0);
      }
    }
    if (t<7) cvtWriteA(cur^1);
    cur ^= 1;
  }

  #pragma unroll
  for (int j=0;j<4;j++){
    int wcol = col0 + wc*64 + j*16 + ml;
    float bv = bsel ? bsel[wcol] : 0.f;
    int c = cbase + wcol;
    #pragma unroll
    for (int mi=0;mi<2;mi++){
      int rb = row0 + wr*32 + mi*16 + quad*4;
      f32x4 av = acc[mi][j];
      #pragma unroll
      for (int r=0;r<4;r++){
        int rr = rb + r;
        if (rr < M){
          float v = av[r] + bv;
          if (RELU) v = fmaxf(v, 0.f);
          Cout[(size_t)rr*cst + c] = v;
        }
      }
    }
  }
}

// ---------------------------------------------------------------------------
// Hyperedge aggregation job (one hyperedge, 256 threads x 2 cols)
// ---------------------------------------------------------------------------
__device__ void edge_job(const MegaArgs& a, int e, const float* X){
  int d = e/57, r = e - d*57;
  int col = threadIdx.x*2;
  float sx=0.f, sy=0.f, de=0.f;
  if (r < 3){
    int nnz0 = d*324 + r*54;
    const float* row = X + ((size_t)(d*162 + r*54))*512 + col;
    for (int i=0;i<54;i++){
      float w = a.ew_w[nnz0+i];
      float2 x = *(const float2*)row;
      sx += w*x.x; sy += w*x.y; de += w;
      row += 512;
    }
  } else {
    int i = r-3;
    int nnz0 = d*324 + 162 + i*3;
    #pragma unroll
    for (int m=0;m<3;m++){
      float w = a.ew_w[nnz0+m];
      const float* row = X + ((size_t)(d*162 + m*54 + i))*512 + col;
      float2 x = *(const float2*)row;
      sx += w*x.x; sy += w*x.y; de += w;
    }
  }
  float invde = 1.0f/(de + 1e-8f);
  const float* at = a.het[e] ? a.attr1 : a.attr2;
  float2 o;
  o.x = sx*invde + at[col];
  o.y = sy*invde + at[col+1];
  *(float2*)(a.EB + (size_t)e*512 + col) = o;
}

// ---------------------------------------------------------------------------
// Gsum of X1 job: per (group, speaker) column sums (idx 0..95)
// ---------------------------------------------------------------------------
__device__ void gsum_job(const MegaArgs& a, int idx, char* smem){
  int g = idx>>1, d = g/3;
  int col = (idx&1)*256 + threadIdx.x;
  unsigned char* spks = (unsigned char*)smem;
  __syncthreads();
  if (threadIdx.x < 54)
    spks[threadIdx.x] = a.qmask[(threadIdx.x*16+d)*2+1] > a.qmask[(threadIdx.x*16+d)*2];
  __syncthreads();
  size_t base = (size_t)g*54*512 + col;
  float s0=0.f, s1=0.f;
  for (int i=0;i<54;i++){
    float x = a.X1[base + (size_t)i*512];
    if (spks[i]) s1 += x; else s0 += x;
  }
  a.Gsum[(size_t)(g*2)*512 + col]   = s0;
  a.Gsum[(size_t)(g*2+1)*512 + col] = s1;
}

// ---------------------------------------------------------------------------
// Fused RGCN combine job: f = relu((S1+S0)*inv + hs); g += f; emits Gsum.
// last: also dout = OUT + g, sum(f^2) -> acc (atomicAdd per job-block).
// ---------------------------------------------------------------------------
__device__ void sf_job(const MegaArgs& a, int j, const float* gin, bool last, char* smem){
  int g = j>>1, d = g/3;
  int col = (j&1)*256 + threadIdx.x;
  unsigned char* spks = (unsigned char*)smem;
  float* red = (float*)(smem + 64);
  if (threadIdx.x < 54)
    spks[threadIdx.x] = a.qmask[(threadIdx.x*16+d)*2+1] > a.qmask[(threadIdx.x*16+d)*2];
  __syncthreads();
  const float* r0 = a.Sp + (size_t)(g*2)*1024;
  const float* r1 = a.Sp + (size_t)(g*2+1)*1024;
  float S1_0 = r0[512+col];
  float S1_1 = r1[512+col];
  float S0_0 = r1[col];
  float S0_1 = r0[col];
  size_t base = (size_t)g*54*512 + col;
  float gs0=0.f, gs1=0.f, sumsq=0.f;
  for (int i=0;i<54;i++){
    size_t off = base + (size_t)i*512;
    int sp = spks[i];
    float S1 = sp ? S1_1 : S1_0;
    float S0 = sp ? S0_1 : S0_0;
    float hs = a.HS[off], gi = gin[off];
    float f = fmaxf((S1 + S0)*INV53 + hs, 0.f);
    float gn = gi + f;
    a.G[off] = gn;
    if (sp) gs1 += gn; else gs0 += gn;
    if (last){
      sumsq += f*f;
      a.dout[off] = a.OUT[off] + gn;
    }
  }
  a.Gsum[(size_t)(g*2)*512 + col]   = gs0;
  a.Gsum[(size_t)(g*2+1)*512 + col] = gs1;
  if (last){
    red[threadIdx.x] = sumsq;
    __syncthreads();
    #pragma unroll
    for (int s=128; s>0; s>>=1){
      if (threadIdx.x < s) red[threadIdx.x] += red[threadIdx.x+s];
      __syncthreads();
    }
    if (threadIdx.x == 0) atomicAdd(a.acc, red[0]);
  }
}

// ---------------------------------------------------------------------------
// Persistent mega-kernel: all 13 stages, separated by grid-wide barriers.
// ---------------------------------------------------------------------------
__global__ __launch_bounds__(256) void mega(MegaArgs a)
{
  __shared__ __align__(16) char smem[53248];
  const int bid = blockIdx.x;
  unsigned int tgt = 0;

  // S0: weight transpose/convert (1024 tile jobs)
  for (int j=bid; j<1024; j+=NBLK) transpose_job(a, j, smem);
  tgt += NBLK; gsync(a.bar, tgt);

  // S1: x1 = feats @ fc1 + b (164 tiles)
  if (bid < 164)
    gemm_tile<0,false>(bid>>2, bid&3, 0, nullptr, nullptr, a.A_in, a.V_in, a.L_in,
                       a.qmask, a.spk, nullptr, a.WT, a.fc1_b, a.X1, nullptr, 0, smem);
  tgt += NBLK; gsync(a.bar, tgt);

  // hypergraph conv x3
  const float* src = a.X1;
  for (int ll=0; ll<3; ll++){
    int njob = (ll==0) ? (NEDGE+96) : NEDGE;
    for (int j=bid; j<njob; j+=NBLK){
      if (j < NEDGE) edge_job(a, j, src);
      else           gsum_job(a, j-NEDGE, smem);
    }
    tgt += NBLK; gsync(a.bar, tgt);
    if (bid < 164)
      gemm_tile<1,true>(bid>>2, bid&3, 0, nullptr, a.EB,
                        nullptr,nullptr,nullptr,nullptr,nullptr, a.he_w,
                        a.WT + (size_t)(1+ll)*MATSZ, a.hc_b + (size_t)ll*512,
                        a.OUT, nullptr, 0, smem);
    tgt += NBLK; gsync(a.bar, tgt);
    src = a.OUT;
  }

  // RGCN denoise x4
  for (int kk=0; kk<4; kk++){
    const float* gin = (kk==0) ? a.X1 : a.G;
    if (bid < 164)
      gemm_tile<2,false>(bid>>2, bid&3, 0, gin, a.Gsum,
                         nullptr,nullptr,nullptr,nullptr,nullptr,nullptr,
                         a.WT, a.m3_b, a.HS, a.Sp, kk, smem);
    else if (bid < 180){
      int q = bid - 164;
      gemm_tile<2,false>(q>>2, q&3, 1, gin, a.Gsum,
                         nullptr,nullptr,nullptr,nullptr,nullptr,nullptr,
                         a.WT, a.m3_b, a.HS, a.Sp, kk, smem);
    }
    tgt += NBLK; gsync(a.bar, tgt);
    if (bid < 96) sf_job(a, bid, gin, (kk==3), smem);
    tgt += NBLK; gsync(a.bar, tgt);
  }

  // finalize denoise scalar (all sf atomicAdds visible after last gsync)
  if (bid==0 && threadIdx.x==0)
    a.dout[(size_t)NNODE*512] = *a.acc * (1.0f/1327104.0f);
}

__global__ void init_kernel(unsigned int* bar, float* acc){
  if (threadIdx.x==0){ *bar = 0u; *acc = 0.0f; }
}

// ---------------------------------------------------------------------------
extern "C" void kernel_launch(void* const* d_in, const int* in_sizes, int n_in,
                              void* d_out, int out_size, void* d_ws, size_t ws_size,
                              hipStream_t stream)
{
  MegaArgs a;
  a.A_in   = (const float*)d_in[0];
  a.V_in   = (const float*)d_in[1];
  a.L_in   = (const float*)d_in[2];
  a.qmask  = (const float*)d_in[3];
  a.spk    = (const float*)d_in[4];
  a.fc1_W  = (const float*)d_in[5];
  a.fc1_b  = (const float*)d_in[6];
  a.he_w   = (const float*)d_in[7];
  a.ew_w   = (const float*)d_in[8];
  a.attr1  = (const float*)d_in[9];
  a.attr2  = (const float*)d_in[10];
  a.hc_W   = (const float*)d_in[11];
  a.hc_b   = (const float*)d_in[12];
  a.m3_W0  = (const float*)d_in[13];
  a.m3_W1  = (const float*)d_in[14];
  a.m3_Ws  = (const float*)d_in[15];
  a.m3_b   = (const float*)d_in[16];
  a.het    = (const int*)d_in[18];
  a.dout   = (float*)d_out;

  char* ws = (char*)d_ws;
  a.WT   = (ushort_t*)ws;                             // 16 * 512KB bf16 = 8 MB
  a.X1   = (float*)(ws + (size_t)16*MATSZ*2);
  a.OUT  = a.X1  + (size_t)NNODE*512;
  float* H1 = a.OUT + (size_t)NNODE*512;              // slot kept (unused)
  a.HS   = H1   + (size_t)NNODE*512;
  a.G    = a.HS + (size_t)NNODE*512;
  a.EB   = a.G  + (size_t)NNODE*512;                  // NEDGE*512
  a.Gsum = a.EB + (size_t)NEDGE*512;                  // 96*512
  a.Sp   = a.Gsum + 96*512;                           // 96*1024
  a.acc  = a.Sp + 96*1024;
  a.bar  = (unsigned int*)(a.acc + 1);

  init_kernel<<<1,64,0,stream>>>(a.bar, a.acc);
  mega<<<NBLK,256,0,stream>>>(a);

  (void)in_sizes; (void)n_in; (void)out_size; (void)ws_size;
}